// Round 1
// baseline (678.474 us; speedup 1.0000x reference)
//
#include <hip/hip_runtime.h>
#include <hip/hip_bf16.h>
#include <math.h>

// Problem constants (from reference): B=2,S=2048,D=1024,F=4096,E=8,K=2
#define Dv 1024
#define Fv 4096
#define Ev 8
#define Tt 4096
#define CAP 2048

typedef unsigned int u32;
typedef __bf16 bf16x8 __attribute__((ext_vector_type(8)));
typedef float f32x4 __attribute__((ext_vector_type(4)));

__device__ __forceinline__ unsigned short f2bf(float f) {
  u32 u = __float_as_uint(f);
  u32 r = (u + 0x7fffu + ((u >> 16) & 1u)) >> 16;
  return (unsigned short)r;
}

__device__ __forceinline__ void gload_lds16(const void* g, void* l) {
  __builtin_amdgcn_global_load_lds(
      (const __attribute__((address_space(1))) u32*)g,
      (__attribute__((address_space(3))) u32*)l, 16, 0, 0);
}

// ---------- transpose fp32 [R,C] -> bf16 [C,R], per expert (blockIdx.z) ----------
__global__ void __launch_bounds__(256)
transpose_bf16_kernel(const float* __restrict__ src, unsigned short* __restrict__ dst,
                      int R, int Cc) {
  __shared__ float tile[32][33];
  int e = blockIdx.z;
  src += (size_t)e * R * Cc;
  dst += (size_t)e * R * Cc;
  int c0 = blockIdx.x * 32, r0 = blockIdx.y * 32;
  int tx = threadIdx.x & 31, ty = threadIdx.x >> 5;  // 32 x 8
#pragma unroll
  for (int i = ty; i < 32; i += 8)
    tile[i][tx] = src[(size_t)(r0 + i) * Cc + (c0 + tx)];
  __syncthreads();
#pragma unroll
  for (int i = ty; i < 32; i += 8)
    dst[(size_t)(c0 + i) * R + (r0 + tx)] = f2bf(tile[tx][i]);
}

// ---------- gating: one wave per token, fp32 ----------
__global__ void __launch_bounds__(256)
gating_kernel(const float* __restrict__ x, const float* __restrict__ Wg,
              int* __restrict__ idx1, int* __restrict__ idx2,
              float* __restrict__ w1, float* __restrict__ w2) {
  int t = blockIdx.x * 4 + (threadIdx.x >> 6);
  int lane = threadIdx.x & 63;
  const float* xr = x + (size_t)t * Dv;
  float acc[Ev];
#pragma unroll
  for (int e = 0; e < Ev; ++e) acc[e] = 0.f;
#pragma unroll
  for (int j = 0; j < 4; ++j) {
    int dbase = (lane + 64 * j) * 4;
    float4 xv = *(const float4*)(xr + dbase);
    const float* wr = Wg + (size_t)dbase * Ev;
#pragma unroll
    for (int u = 0; u < 4; ++u) {
      float xd = (&xv.x)[u];
#pragma unroll
      for (int e = 0; e < Ev; ++e) acc[e] += xd * wr[u * Ev + e];
    }
  }
#pragma unroll
  for (int off = 32; off > 0; off >>= 1) {
#pragma unroll
    for (int e = 0; e < Ev; ++e) acc[e] += __shfl_xor(acc[e], off, 64);
  }
  if (lane == 0) {
    // first-occurrence argmax over logits (== argmax over softmax gates)
    float mx = acc[0]; int i1 = 0;
#pragma unroll
    for (int e = 1; e < Ev; ++e) { if (acc[e] > mx) { mx = acc[e]; i1 = e; } }
    float ge[Ev]; float se = 0.f;
#pragma unroll
    for (int e = 0; e < Ev; ++e) { ge[e] = expf(acc[e] - mx); se += ge[e]; }
    // second argmax (mask i1), first occurrence
    float mx2 = -INFINITY; int i2 = 0; bool have = false;
#pragma unroll
    for (int e = 0; e < Ev; ++e) {
      if (e == i1) continue;
      if (!have || acc[e] > mx2) { mx2 = acc[e]; i2 = e; have = true; }
    }
    float g1 = 0.f, g2 = 0.f;
#pragma unroll
    for (int e = 0; e < Ev; ++e) { if (e == i1) g1 = ge[e]; if (e == i2) g2 = ge[e]; }
    g1 /= se; g2 /= se;
    float denom = g1 + g2 + 1e-9f;
    idx1[t] = i1; idx2[t] = i2;
    w1[t] = g1 / denom; w2[t] = g2 / denom;
  }
}

// ---------- GShard slot assignment scan (single block) ----------
__global__ void __launch_bounds__(256)
scan_kernel(const int* __restrict__ gidx1, const int* __restrict__ gidx2,
            const float* __restrict__ gw1, const float* __restrict__ gw2,
            int* __restrict__ pos1, int* __restrict__ pos2,
            float* __restrict__ w1k, float* __restrict__ w2k,
            int* __restrict__ n_e) {
  __shared__ short s1[Tt], s2[Tt];
  __shared__ int c1[256][Ev], c2[256][Ev];
  __shared__ int tot1[Ev], tot2[Ev];
  int tid = threadIdx.x;
  for (int i = tid; i < Tt; i += 256) { s1[i] = (short)gidx1[i]; s2[i] = (short)gidx2[i]; }
  __syncthreads();
  int base = tid * 16;
  {
    int l1[Ev], l2[Ev];
#pragma unroll
    for (int e = 0; e < Ev; ++e) { l1[e] = 0; l2[e] = 0; }
    for (int j = 0; j < 16; ++j) {
      int a = s1[base + j], b = s2[base + j];
#pragma unroll
      for (int e = 0; e < Ev; ++e) { l1[e] += (a == e); l2[e] += (b == e); }
    }
#pragma unroll
    for (int e = 0; e < Ev; ++e) { c1[tid][e] = l1[e]; c2[tid][e] = l2[e]; }
  }
  __syncthreads();
  if (tid < Ev) {
    int run = 0;
    for (int c = 0; c < 256; ++c) { int v = c1[c][tid]; c1[c][tid] = run; run += v; }
    tot1[tid] = run;
  } else if (tid < 2 * Ev) {
    int e = tid - Ev; int run = 0;
    for (int c = 0; c < 256; ++c) { int v = c2[c][e]; c2[c][e] = run; run += v; }
    tot2[e] = run;
  }
  __syncthreads();
  if (tid < Ev) {
    int ne = tot1[tid] + tot2[tid];
    n_e[tid] = ne < CAP ? ne : CAP;
  }
  int r1[Ev], r2[Ev];
#pragma unroll
  for (int e = 0; e < Ev; ++e) { r1[e] = c1[tid][e]; r2[e] = c2[tid][e] + tot1[e]; }
  for (int j = 0; j < 16; ++j) {
    int tk = base + j;
    int e1 = s1[tk], e2 = s2[tk];
    int p1 = 0, p2 = 0;
#pragma unroll
    for (int e = 0; e < Ev; ++e) {
      if (e == e1) { p1 = r1[e]; r1[e]++; }
      if (e == e2) { p2 = r2[e]; r2[e]++; }
    }
    bool k1 = p1 < CAP, k2 = p2 < CAP;
    pos1[tk] = k1 ? p1 : -1;
    pos2[tk] = k2 ? p2 : -1;
    w1k[tk] = k1 ? gw1[tk] : 0.f;
    w2k[tk] = k2 ? gw2[tk] : 0.f;
  }
}

// ---------- dispatch: scatter token rows to expert slots (bf16) ----------
__global__ void __launch_bounds__(256)
dispatch_kernel(const float* __restrict__ x,
                const int* __restrict__ idx1, const int* __restrict__ idx2,
                const int* __restrict__ pos1, const int* __restrict__ pos2,
                unsigned short* __restrict__ Xe) {
  int t = blockIdx.x, tid = threadIdx.x;
  float4 xv = *(const float4*)(x + (size_t)t * Dv + tid * 4);
  ushort4 bv;
  bv.x = f2bf(xv.x); bv.y = f2bf(xv.y); bv.z = f2bf(xv.z); bv.w = f2bf(xv.w);
  int p1 = pos1[t], p2 = pos2[t];
  int e1 = idx1[t], e2 = idx2[t];
  if (p1 >= 0)
    *(ushort4*)(Xe + ((size_t)(e1 * CAP + p1)) * Dv + tid * 4) = bv;
  if (p2 >= 0)
    *(ushort4*)(Xe + ((size_t)(e2 * CAP + p2)) * Dv + tid * 4) = bv;
}

// ---------- m97-pattern bf16 GEMM: C[e] = A[e][M,K] * Bt[e][N,K]^T ----------
// MODE 0: out = bf16(gelu(acc + bias))  (fc1 -> h)
// MODE 1: out = fp32(acc + bias)        (fc2 -> ye)
template <int MODE>
__global__ void __launch_bounds__(256, 2)
gemm_kernel(const unsigned short* __restrict__ A,
            const unsigned short* __restrict__ Bt,
            const float* __restrict__ bias,
            void* __restrict__ Out,
            const int* __restrict__ n_e,
            int M, int N, int K) {
  int e = blockIdx.z;
  int m0 = blockIdx.y * 128, n0 = blockIdx.x * 128;
  if (m0 >= n_e[e]) return;  // rows >= n_e are never read downstream
  A += (size_t)e * M * K;
  Bt += (size_t)e * N * K;
  bias += (size_t)e * N;
  __shared__ unsigned short As[128 * 32];
  __shared__ unsigned short Bs[128 * 32];
  int tid = threadIdx.x;
  int wave = tid >> 6, lane = tid & 63;
  int wm = (wave & 1) * 64, wn = (wave >> 1) * 64;
  int quad = lane >> 4, lr = lane & 15;
  f32x4 acc[4][4];
#pragma unroll
  for (int i = 0; i < 4; ++i)
#pragma unroll
    for (int j = 0; j < 4; ++j)
#pragma unroll
      for (int r = 0; r < 4; ++r) acc[i][j][r] = 0.f;

  int srow = tid >> 2, scol = (tid & 3) * 8;
  const unsigned short* ga = A + (size_t)(m0 + srow) * K + scol;
  const unsigned short* gb = Bt + (size_t)(n0 + srow) * K + scol;
  unsigned short* la = &As[srow * 32 + scol];
  unsigned short* lb = &Bs[srow * 32 + scol];

  for (int k0 = 0; k0 < K; k0 += 32) {
    __syncthreads();
    gload_lds16(ga + k0, la);
    gload_lds16(ga + (size_t)64 * K + k0, la + 64 * 32);
    gload_lds16(gb + k0, lb);
    gload_lds16(gb + (size_t)64 * K + k0, lb + 64 * 32);
    __syncthreads();
    bf16x8 af[4], bfr[4];
#pragma unroll
    for (int mi = 0; mi < 4; ++mi)
      af[mi] = *(const bf16x8*)&As[(wm + mi * 16 + lr) * 32 + quad * 8];
#pragma unroll
    for (int ni = 0; ni < 4; ++ni)
      bfr[ni] = *(const bf16x8*)&Bs[(wn + ni * 16 + lr) * 32 + quad * 8];
#pragma unroll
    for (int mi = 0; mi < 4; ++mi)
#pragma unroll
      for (int ni = 0; ni < 4; ++ni)
        acc[mi][ni] = __builtin_amdgcn_mfma_f32_16x16x32_bf16(af[mi], bfr[ni], acc[mi][ni], 0, 0, 0);
  }

#pragma unroll
  for (int ni = 0; ni < 4; ++ni) {
    int col = n0 + wn + ni * 16 + lr;
    float bv = bias[col];
#pragma unroll
    for (int mi = 0; mi < 4; ++mi) {
#pragma unroll
      for (int r = 0; r < 4; ++r) {
        int row = m0 + wm + mi * 16 + quad * 4 + r;
        float v = acc[mi][ni][r] + bv;
        if (MODE == 0) {
          v = 0.5f * v * (1.0f + erff(v * 0.70710678118654752f));
          ((unsigned short*)Out)[((size_t)e * M + row) * N + col] = f2bf(v);
        } else {
          ((float*)Out)[((size_t)e * M + row) * N + col] = v;
        }
      }
    }
  }
}

// ---------- combine ----------
__global__ void __launch_bounds__(256)
combine_kernel(const float* __restrict__ ye,
               const int* __restrict__ idx1, const int* __restrict__ idx2,
               const int* __restrict__ pos1, const int* __restrict__ pos2,
               const float* __restrict__ w1k, const float* __restrict__ w2k,
               float* __restrict__ out) {
  int t = blockIdx.x, tid = threadIdx.x;
  int p1 = pos1[t], p2 = pos2[t];
  float a1 = w1k[t], a2 = w2k[t];
  float4 o = make_float4(0.f, 0.f, 0.f, 0.f);
  if (p1 >= 0) {
    float4 y = *(const float4*)(ye + ((size_t)(idx1[t] * CAP + p1)) * Dv + tid * 4);
    o.x += a1 * y.x; o.y += a1 * y.y; o.z += a1 * y.z; o.w += a1 * y.w;
  }
  if (p2 >= 0) {
    float4 y = *(const float4*)(ye + ((size_t)(idx2[t] * CAP + p2)) * Dv + tid * 4);
    o.x += a2 * y.x; o.y += a2 * y.y; o.z += a2 * y.z; o.w += a2 * y.w;
  }
  *(float4*)(out + (size_t)t * Dv + tid * 4) = o;
}

extern "C" void kernel_launch(void* const* d_in, const int* in_sizes, int n_in,
                              void* d_out, int out_size, void* d_ws, size_t ws_size,
                              hipStream_t stream) {
  const float* x  = (const float*)d_in[0];
  const float* Wg = (const float*)d_in[1];
  const float* W1 = (const float*)d_in[2];
  const float* b1 = (const float*)d_in[3];
  const float* W2 = (const float*)d_in[4];
  const float* b2 = (const float*)d_in[5];
  float* out = (float*)d_out;

  // workspace layout (ye aliases Wt1, which is dead after fc1)
  char* p = (char*)d_ws;
  size_t off = 0;
  auto alloc = [&](size_t bytes) {
    void* q = p + off;
    off += (bytes + 255) & ~(size_t)255;
    return q;
  };
  unsigned short* Wt1 = (unsigned short*)alloc((size_t)Ev * Fv * Dv * 2);  // 64MB, aliased by ye
  unsigned short* Wt2 = (unsigned short*)alloc((size_t)Ev * Dv * Fv * 2);  // 64MB
  unsigned short* Xe  = (unsigned short*)alloc((size_t)Ev * CAP * Dv * 2); // 32MB
  unsigned short* h   = (unsigned short*)alloc((size_t)Ev * CAP * Fv * 2); // 128MB
  int*   idx1 = (int*)alloc(Tt * 4);
  int*   idx2 = (int*)alloc(Tt * 4);
  int*   pos1 = (int*)alloc(Tt * 4);
  int*   pos2 = (int*)alloc(Tt * 4);
  float* w1   = (float*)alloc(Tt * 4);
  float* w2   = (float*)alloc(Tt * 4);
  float* w1k  = (float*)alloc(Tt * 4);
  float* w2k  = (float*)alloc(Tt * 4);
  int*   n_e  = (int*)alloc(Ev * 4);
  float* ye   = (float*)Wt1;  // [E][CAP][Dv] fp32, 64MB, aliases Wt1

  // 1) weight transpose+convert: W1[E,D,F] -> Wt1[E,F,D]; W2[E,F,D] -> Wt2[E,D,F]
  transpose_bf16_kernel<<<dim3(Fv / 32, Dv / 32, Ev), 256, 0, stream>>>(W1, Wt1, Dv, Fv);
  transpose_bf16_kernel<<<dim3(Dv / 32, Fv / 32, Ev), 256, 0, stream>>>(W2, Wt2, Fv, Dv);
  // 2) gating
  gating_kernel<<<Tt / 4, 256, 0, stream>>>(x, Wg, idx1, idx2, w1, w2);
  // 3) slot assignment
  scan_kernel<<<1, 256, 0, stream>>>(idx1, idx2, w1, w2, pos1, pos2, w1k, w2k, n_e);
  // 4) dispatch
  dispatch_kernel<<<Tt, 256, 0, stream>>>(x, idx1, idx2, pos1, pos2, Xe);
  // 5) fc1: h = gelu(Xe @ W1 + b1)   [M=CAP, N=F, K=D]
  gemm_kernel<0><<<dim3(Fv / 128, CAP / 128, Ev), 256, 0, stream>>>(
      Xe, Wt1, b1, h, n_e, CAP, Fv, Dv);
  // 6) fc2: ye = h @ W2 + b2         [M=CAP, N=D, K=F]
  gemm_kernel<1><<<dim3(Dv / 128, CAP / 128, Ev), 256, 0, stream>>>(
      h, Wt2, b2, ye, n_e, CAP, Dv, Fv);
  // 7) combine
  combine_kernel<<<Tt, 256, 0, stream>>>(ye, idx1, idx2, pos1, pos2, w1k, w2k, out);
}

// Round 2
// 622.038 us; speedup vs baseline: 1.0907x; 1.0907x over previous
//
#include <hip/hip_runtime.h>
#include <hip/hip_bf16.h>
#include <math.h>

// Problem constants (from reference): B=2,S=2048,D=1024,F=4096,E=8,K=2
#define Dv 1024
#define Fv 4096
#define Ev 8
#define Tt 4096
#define CAP 2048

typedef unsigned int u32;
typedef __bf16 bf16x8 __attribute__((ext_vector_type(8)));
typedef float f32x4 __attribute__((ext_vector_type(4)));

__device__ __forceinline__ unsigned short f2bf(float f) {
  u32 u = __float_as_uint(f);
  u32 r = (u + 0x7fffu + ((u >> 16) & 1u)) >> 16;
  return (unsigned short)r;
}

__device__ __forceinline__ void gload_lds16(const void* g, void* l) {
  __builtin_amdgcn_global_load_lds(
      (const __attribute__((address_space(1))) u32*)g,
      (__attribute__((address_space(3))) u32*)l, 16, 0, 0);
}

// ---------- transpose fp32 [R,C] -> bf16 [C,R], per expert (blockIdx.z) ----------
// 64x64 tiles; fp32 LDS staging; ushort2 transposed stores (128B/wave-row).
__global__ void __launch_bounds__(256)
transpose_bf16_kernel(const float* __restrict__ src, unsigned short* __restrict__ dst,
                      int R, int Cc) {
  __shared__ float tile[64][65];
  int e = blockIdx.z;
  src += (size_t)e * R * Cc;
  dst += (size_t)e * R * Cc;
  int c0 = blockIdx.x * 64, r0 = blockIdx.y * 64;
  int tc = threadIdx.x & 63, tr = threadIdx.x >> 6;  // 64 x 4
#pragma unroll
  for (int i = tr; i < 64; i += 4)
    tile[i][tc] = src[(size_t)(r0 + i) * Cc + (c0 + tc)];
  __syncthreads();
  int rp = (threadIdx.x & 31) * 2, co = threadIdx.x >> 5;  // 32 x 8
#pragma unroll
  for (int k = 0; k < 8; ++k) {
    int c = co + 8 * k;
    ushort2 v;
    v.x = f2bf(tile[rp][c]);
    v.y = f2bf(tile[rp + 1][c]);
    *(ushort2*)&dst[(size_t)(c0 + c) * R + (r0 + rp)] = v;
  }
}

// ---------- gating: one wave per token, fp32 ----------
__global__ void __launch_bounds__(256)
gating_kernel(const float* __restrict__ x, const float* __restrict__ Wg,
              int* __restrict__ idx1, int* __restrict__ idx2,
              float* __restrict__ w1, float* __restrict__ w2) {
  int t = blockIdx.x * 4 + (threadIdx.x >> 6);
  int lane = threadIdx.x & 63;
  const float* xr = x + (size_t)t * Dv;
  float acc[Ev];
#pragma unroll
  for (int e = 0; e < Ev; ++e) acc[e] = 0.f;
#pragma unroll
  for (int j = 0; j < 4; ++j) {
    int dbase = (lane + 64 * j) * 4;
    float4 xv = *(const float4*)(xr + dbase);
    const float* wr = Wg + (size_t)dbase * Ev;
#pragma unroll
    for (int u = 0; u < 4; ++u) {
      float xd = (&xv.x)[u];
#pragma unroll
      for (int e = 0; e < Ev; ++e) acc[e] += xd * wr[u * Ev + e];
    }
  }
#pragma unroll
  for (int off = 32; off > 0; off >>= 1) {
#pragma unroll
    for (int e = 0; e < Ev; ++e) acc[e] += __shfl_xor(acc[e], off, 64);
  }
  if (lane == 0) {
    float mx = acc[0]; int i1 = 0;
#pragma unroll
    for (int e = 1; e < Ev; ++e) { if (acc[e] > mx) { mx = acc[e]; i1 = e; } }
    float ge[Ev]; float se = 0.f;
#pragma unroll
    for (int e = 0; e < Ev; ++e) { ge[e] = expf(acc[e] - mx); se += ge[e]; }
    float mx2 = -INFINITY; int i2 = 0; bool have = false;
#pragma unroll
    for (int e = 0; e < Ev; ++e) {
      if (e == i1) continue;
      if (!have || acc[e] > mx2) { mx2 = acc[e]; i2 = e; have = true; }
    }
    float g1 = 0.f, g2 = 0.f;
#pragma unroll
    for (int e = 0; e < Ev; ++e) { if (e == i1) g1 = ge[e]; if (e == i2) g2 = ge[e]; }
    g1 /= se; g2 /= se;
    float denom = g1 + g2 + 1e-9f;
    idx1[t] = i1; idx2[t] = i2;
    w1[t] = g1 / denom; w2[t] = g2 / denom;
  }
}

// ---------- GShard slot assignment scan (single block) ----------
__global__ void __launch_bounds__(256)
scan_kernel(const int* __restrict__ gidx1, const int* __restrict__ gidx2,
            const float* __restrict__ gw1, const float* __restrict__ gw2,
            int* __restrict__ pos1, int* __restrict__ pos2,
            float* __restrict__ w1k, float* __restrict__ w2k,
            int* __restrict__ n_e) {
  __shared__ short s1[Tt], s2[Tt];
  __shared__ int c1[256][Ev], c2[256][Ev];
  __shared__ int tot1[Ev], tot2[Ev];
  int tid = threadIdx.x;
  for (int i = tid; i < Tt; i += 256) { s1[i] = (short)gidx1[i]; s2[i] = (short)gidx2[i]; }
  __syncthreads();
  int base = tid * 16;
  {
    int l1[Ev], l2[Ev];
#pragma unroll
    for (int e = 0; e < Ev; ++e) { l1[e] = 0; l2[e] = 0; }
    for (int j = 0; j < 16; ++j) {
      int a = s1[base + j], b = s2[base + j];
#pragma unroll
      for (int e = 0; e < Ev; ++e) { l1[e] += (a == e); l2[e] += (b == e); }
    }
#pragma unroll
    for (int e = 0; e < Ev; ++e) { c1[tid][e] = l1[e]; c2[tid][e] = l2[e]; }
  }
  __syncthreads();
  if (tid < Ev) {
    int run = 0;
    for (int c = 0; c < 256; ++c) { int v = c1[c][tid]; c1[c][tid] = run; run += v; }
    tot1[tid] = run;
  } else if (tid < 2 * Ev) {
    int e = tid - Ev; int run = 0;
    for (int c = 0; c < 256; ++c) { int v = c2[c][e]; c2[c][e] = run; run += v; }
    tot2[e] = run;
  }
  __syncthreads();
  if (tid < Ev) {
    int ne = tot1[tid] + tot2[tid];
    n_e[tid] = ne < CAP ? ne : CAP;
  }
  int r1[Ev], r2[Ev];
#pragma unroll
  for (int e = 0; e < Ev; ++e) { r1[e] = c1[tid][e]; r2[e] = c2[tid][e] + tot1[e]; }
  for (int j = 0; j < 16; ++j) {
    int tk = base + j;
    int e1 = s1[tk], e2 = s2[tk];
    int p1 = 0, p2 = 0;
#pragma unroll
    for (int e = 0; e < Ev; ++e) {
      if (e == e1) { p1 = r1[e]; r1[e]++; }
      if (e == e2) { p2 = r2[e]; r2[e]++; }
    }
    bool k1 = p1 < CAP, k2 = p2 < CAP;
    pos1[tk] = k1 ? p1 : -1;
    pos2[tk] = k2 ? p2 : -1;
    w1k[tk] = k1 ? gw1[tk] : 0.f;
    w2k[tk] = k2 ? gw2[tk] : 0.f;
  }
}

// ---------- dispatch: scatter token rows to expert slots (bf16) ----------
__global__ void __launch_bounds__(256)
dispatch_kernel(const float* __restrict__ x,
                const int* __restrict__ idx1, const int* __restrict__ idx2,
                const int* __restrict__ pos1, const int* __restrict__ pos2,
                unsigned short* __restrict__ Xe) {
  int t = blockIdx.x, tid = threadIdx.x;
  float4 xv = *(const float4*)(x + (size_t)t * Dv + tid * 4);
  ushort4 bv;
  bv.x = f2bf(xv.x); bv.y = f2bf(xv.y); bv.z = f2bf(xv.z); bv.w = f2bf(xv.w);
  int p1 = pos1[t], p2 = pos2[t];
  int e1 = idx1[t], e2 = idx2[t];
  if (p1 >= 0)
    *(ushort4*)(Xe + ((size_t)(e1 * CAP + p1)) * Dv + tid * 4) = bv;
  if (p2 >= 0)
    *(ushort4*)(Xe + ((size_t)(e2 * CAP + p2)) * Dv + tid * 4) = bv;
}

// ---------- bf16 GEMM, BK=64, XOR-swizzled LDS: C[e] = A[e][M,K] * Bt[e][N,K]^T ----------
// LDS granule layout: row r, dest granule g (16B) holds global granule g^(r&7).
// MODE 0: out = bf16(gelu(acc + bias))  (fc1 -> h)
// MODE 1: out = fp32(acc + bias)        (fc2 -> ye)
template <int MODE>
__global__ void __launch_bounds__(256, 2)
gemm_kernel(const unsigned short* __restrict__ A,
            const unsigned short* __restrict__ Bt,
            const float* __restrict__ bias,
            void* __restrict__ Out,
            const int* __restrict__ n_e,
            int M, int N, int K) {
  int e = blockIdx.z;
  int m0 = blockIdx.y * 128, n0 = blockIdx.x * 128;
  if (m0 >= n_e[e]) return;  // rows >= n_e are never read downstream
  A += (size_t)e * M * K;
  Bt += (size_t)e * N * K;
  bias += (size_t)e * N;
  __shared__ unsigned short As[128 * 64];
  __shared__ unsigned short Bs[128 * 64];
  int tid = threadIdx.x;
  int wave = tid >> 6, lane = tid & 63;
  int wm = (wave & 1) * 64, wn = (wave >> 1) * 64;
  int quad = lane >> 4, lr = lane & 15;
  int sw = lr & 7;
  f32x4 acc[4][4];
#pragma unroll
  for (int i = 0; i < 4; ++i)
#pragma unroll
    for (int j = 0; j < 4; ++j)
#pragma unroll
      for (int r = 0; r < 4; ++r) acc[i][j][r] = 0.f;

  // staging: instruction s covers rows s*32 + (tid>>3), granule tid&7.
  // source granule is XOR-swizzled so fragment reads are bank-conflict-free.
  int r_st = tid >> 3;          // 0..31
  int g_st = tid & 7;
  int gsrc = g_st ^ (r_st & 7);
  const unsigned short* gA = A + (size_t)(m0 + r_st) * K + gsrc * 8;
  const unsigned short* gB = Bt + (size_t)(n0 + r_st) * K + gsrc * 8;
  unsigned short* lA = &As[tid * 8];
  unsigned short* lB = &Bs[tid * 8];

  for (int k0 = 0; k0 < K; k0 += 64) {
    __syncthreads();
#pragma unroll
    for (int s = 0; s < 4; ++s) {
      gload_lds16(gA + (size_t)(s * 32) * K + k0, lA + s * 2048);
      gload_lds16(gB + (size_t)(s * 32) * K + k0, lB + s * 2048);
    }
    __syncthreads();
#pragma unroll
    for (int h = 0; h < 2; ++h) {
      bf16x8 af[4], bfr[4];
#pragma unroll
      for (int mi = 0; mi < 4; ++mi) {
        int row = wm + mi * 16 + lr;
        int c = (h * 4 + quad) ^ sw;
        af[mi] = *(const bf16x8*)&As[row * 64 + c * 8];
      }
#pragma unroll
      for (int ni = 0; ni < 4; ++ni) {
        int row = wn + ni * 16 + lr;
        int c = (h * 4 + quad) ^ sw;
        bfr[ni] = *(const bf16x8*)&Bs[row * 64 + c * 8];
      }
#pragma unroll
      for (int mi = 0; mi < 4; ++mi)
#pragma unroll
        for (int ni = 0; ni < 4; ++ni)
          acc[mi][ni] = __builtin_amdgcn_mfma_f32_16x16x32_bf16(af[mi], bfr[ni], acc[mi][ni], 0, 0, 0);
    }
  }

#pragma unroll
  for (int ni = 0; ni < 4; ++ni) {
    int col = n0 + wn + ni * 16 + lr;
    float bv = bias[col];
#pragma unroll
    for (int mi = 0; mi < 4; ++mi) {
#pragma unroll
      for (int r = 0; r < 4; ++r) {
        int row = m0 + wm + mi * 16 + quad * 4 + r;
        float v = acc[mi][ni][r] + bv;
        if (MODE == 0) {
          v = 0.5f * v * (1.0f + erff(v * 0.70710678118654752f));
          ((unsigned short*)Out)[((size_t)e * M + row) * N + col] = f2bf(v);
        } else {
          ((float*)Out)[((size_t)e * M + row) * N + col] = v;
        }
      }
    }
  }
}

// ---------- combine ----------
__global__ void __launch_bounds__(256)
combine_kernel(const float* __restrict__ ye,
               const int* __restrict__ idx1, const int* __restrict__ idx2,
               const int* __restrict__ pos1, const int* __restrict__ pos2,
               const float* __restrict__ w1k, const float* __restrict__ w2k,
               float* __restrict__ out) {
  int t = blockIdx.x, tid = threadIdx.x;
  int p1 = pos1[t], p2 = pos2[t];
  float a1 = w1k[t], a2 = w2k[t];
  float4 o = make_float4(0.f, 0.f, 0.f, 0.f);
  if (p1 >= 0) {
    float4 y = *(const float4*)(ye + ((size_t)(idx1[t] * CAP + p1)) * Dv + tid * 4);
    o.x += a1 * y.x; o.y += a1 * y.y; o.z += a1 * y.z; o.w += a1 * y.w;
  }
  if (p2 >= 0) {
    float4 y = *(const float4*)(ye + ((size_t)(idx2[t] * CAP + p2)) * Dv + tid * 4);
    o.x += a2 * y.x; o.y += a2 * y.y; o.z += a2 * y.z; o.w += a2 * y.w;
  }
  *(float4*)(out + (size_t)t * Dv + tid * 4) = o;
}

extern "C" void kernel_launch(void* const* d_in, const int* in_sizes, int n_in,
                              void* d_out, int out_size, void* d_ws, size_t ws_size,
                              hipStream_t stream) {
  const float* x  = (const float*)d_in[0];
  const float* Wg = (const float*)d_in[1];
  const float* W1 = (const float*)d_in[2];
  const float* b1 = (const float*)d_in[3];
  const float* W2 = (const float*)d_in[4];
  const float* b2 = (const float*)d_in[5];
  float* out = (float*)d_out;

  char* p = (char*)d_ws;
  size_t off = 0;
  auto alloc = [&](size_t bytes) {
    void* q = p + off;
    off += (bytes + 255) & ~(size_t)255;
    return q;
  };
  unsigned short* Wt1 = (unsigned short*)alloc((size_t)Ev * Fv * Dv * 2);  // 64MB, aliased by ye
  unsigned short* Wt2 = (unsigned short*)alloc((size_t)Ev * Dv * Fv * 2);  // 64MB
  unsigned short* Xe  = (unsigned short*)alloc((size_t)Ev * CAP * Dv * 2); // 32MB
  unsigned short* h   = (unsigned short*)alloc((size_t)Ev * CAP * Fv * 2); // 128MB
  int*   idx1 = (int*)alloc(Tt * 4);
  int*   idx2 = (int*)alloc(Tt * 4);
  int*   pos1 = (int*)alloc(Tt * 4);
  int*   pos2 = (int*)alloc(Tt * 4);
  float* w1   = (float*)alloc(Tt * 4);
  float* w2   = (float*)alloc(Tt * 4);
  float* w1k  = (float*)alloc(Tt * 4);
  float* w2k  = (float*)alloc(Tt * 4);
  int*   n_e  = (int*)alloc(Ev * 4);
  float* ye   = (float*)Wt1;  // [E][CAP][Dv] fp32, aliases Wt1 (dead after fc1)

  // 1) weight transpose+convert: W1[E,D,F] -> Wt1[E,F,D]; W2[E,F,D] -> Wt2[E,D,F]
  transpose_bf16_kernel<<<dim3(Fv / 64, Dv / 64, Ev), 256, 0, stream>>>(W1, Wt1, Dv, Fv);
  transpose_bf16_kernel<<<dim3(Dv / 64, Fv / 64, Ev), 256, 0, stream>>>(W2, Wt2, Fv, Dv);
  // 2) gating
  gating_kernel<<<Tt / 4, 256, 0, stream>>>(x, Wg, idx1, idx2, w1, w2);
  // 3) slot assignment
  scan_kernel<<<1, 256, 0, stream>>>(idx1, idx2, w1, w2, pos1, pos2, w1k, w2k, n_e);
  // 4) dispatch
  dispatch_kernel<<<Tt, 256, 0, stream>>>(x, idx1, idx2, pos1, pos2, Xe);
  // 5) fc1: h = gelu(Xe @ W1 + b1)   [M=CAP, N=F, K=D]
  gemm_kernel<0><<<dim3(Fv / 128, CAP / 128, Ev), 256, 0, stream>>>(
      Xe, Wt1, b1, h, n_e, CAP, Fv, Dv);
  // 6) fc2: ye = h @ W2 + b2         [M=CAP, N=D, K=F]
  gemm_kernel<1><<<dim3(Dv / 128, CAP / 128, Ev), 256, 0, stream>>>(
      h, Wt2, b2, ye, n_e, CAP, Dv, Fv);
  // 7) combine
  combine_kernel<<<Tt, 256, 0, stream>>>(ye, idx1, idx2, pos1, pos2, w1k, w2k, out);
}